// Round 9
// baseline (783.458 us; speedup 1.0000x reference)
//
#include <hip/hip_runtime.h>
#include <math.h>

// Problem constants (fixed by reference)
#define DIMD 256
#define KCODES 4096
#define NROWS 65536
#define QN (NROWS * DIMD)   // 16777216 quantized elements

// ---------------- pass1 (bf16 MFMA prune) parameters ----------------
constexpr int P1_BM = 64;      // rows per block (4 waves, 2x2 tiling)
constexpr int P1_BN = 128;     // codes per N-tile
constexpr int NT    = KCODES / P1_BN;   // 32 N-tiles
constexpr int NCHUNK = NT * 2;          // 64 chunks of 128 codes x 128 k
// Dot-scale margin: candidate iff dot > running_global_prefix_max - TAU2.
// Error stack (dot scale): bf16 operand rounding <=2.3e-4 (worst), np fp32
// quantization ~3e-5, dropped se <=0.8e-5  ->  TAU2 = 7.5e-4 is ~2.8x margin.
// Prefix max <= final max at every collection point -> superset of the
// final-max candidate set (E ~ 7/row). Stored word packs the MFMA dot
// (top-20 fp32 bits) + 12-bit code; pass2 recovers the FINAL max and
// re-filters to ~2-3/row before the exact re-rank. Key truncation < 2.5e-6
// covered by the +1e-5 pass2 margin.
constexpr float TAU2 = 7.5e-4f;
constexpr float TAU2B = TAU2 + 1e-5f;   // pass2 re-filter margin (key truncation)
constexpr int CAP   = 48;      // candidate slots per row (overflow -> exact fallback)
constexpr int NS    = 6;       // pass2 LDS staging slots (survivors E~2-3)
constexpr int P2_WAVES = 16384;         // pass2 total waves (4 rows each)

typedef __attribute__((ext_vector_type(8))) short bf16x8;
typedef __attribute__((ext_vector_type(4))) float f32x4;

#define VM8() asm volatile("s_waitcnt vmcnt(8)" ::: "memory")
#define VM0() asm volatile("s_waitcnt vmcnt(0)" ::: "memory")

// RNE float -> bf16 bits (inputs finite; no NaN handling needed)
__device__ __forceinline__ unsigned short f2bf(float f) {
    unsigned int u = __builtin_bit_cast(unsigned int, f);
    u += 0x7fffu + ((u >> 16) & 1u);
    return (unsigned short)(u >> 16);
}

// Opaque barrier: forces v to be a rounded fp32 value (blocks FMA contraction)
__device__ __forceinline__ float opaque(float v) {
    asm volatile("" : "+v"(v));
    return v;
}

// async global->LDS, 16 B per lane, dest = wave-uniform base + lane*16
__device__ __forceinline__ void gload_lds16(const void* g, void* l) {
    __builtin_amdgcn_global_load_lds(
        (const __attribute__((address_space(1))) unsigned int*)g,
        (__attribute__((address_space(3))) unsigned int*)l, 16, 0, 0);
}

// ---------------------------------------------------------------- kernel Sx
// 8 lanes per row; lane j owns np accumulator r[j]. Bit-exact replication of
// the validated serial np pairwise_sum (combine tree via shfl_xor 1/2/4;
// IEEE add commutative -> bit-identical).
__global__ void sx_kernel(const float* __restrict__ x, float* __restrict__ sx) {
    const int j   = threadIdx.x & 7;
    const int row = blockIdx.x * 32 + (threadIdx.x >> 3);
    const float* p = x + (size_t)row * DIMD;
    float total = 0.0f;
    #pragma unroll
    for (int half = 0; half < 2; ++half) {
        const float* b = p + half * 128;
        const float v0 = b[j];
        float r = opaque(v0 * v0);
        #pragma unroll
        for (int i = 8; i < 128; i += 8) {
            const float v = b[i + j];
            r += opaque(v * v);
        }
        const float s1  = r  + __shfl_xor(r, 1, 64);
        const float s2  = s1 + __shfl_xor(s1, 2, 64);
        const float res = s2 + __shfl_xor(s2, 4, 64);
        total = (half == 0) ? res : (total + res);
    }
    if (j == 0) sx[row] = total;
}

// ---------------------------------------------------------------- kernel Se
__global__ void se_kernel(const float* __restrict__ emb, float* __restrict__ se) {
    const int j   = threadIdx.x & 7;
    const int row = blockIdx.x * 32 + (threadIdx.x >> 3);
    const float* p = emb + (size_t)row * DIMD;
    float total = 0.0f;
    #pragma unroll
    for (int half = 0; half < 2; ++half) {
        const float* b = p + half * 128;
        const float v0 = b[j];
        float r = opaque(v0 * v0);
        #pragma unroll
        for (int i = 8; i < 128; i += 8) {
            const float v = b[i + j];
            r += opaque(v * v);
        }
        const float s1  = r  + __shfl_xor(r, 1, 64);
        const float s2  = s1 + __shfl_xor(s1, 2, 64);
        const float res = s2 + __shfl_xor(s2, 4, 64);
        total = (half == 0) ? res : (total + res);
    }
    if (j == 0) se[row] = total;
}

// ---------------------------------------------------------------- conv emb->bf16
__global__ void conv_emb_kernel(const float* __restrict__ emb, unsigned short* __restrict__ embh) {
    const int i = blockIdx.x * blockDim.x + threadIdx.x;  // float4 index
    const float4 v = ((const float4*)emb)[i];
    ushort4 h;
    h.x = f2bf(v.x); h.y = f2bf(v.y); h.z = f2bf(v.z); h.w = f2bf(v.w);
    ((ushort4*)embh)[i] = h;
}

// ---------------------------------------------------------------- kernel P1
// Single-pass bf16 MFMA prune, v6 (validated R8; UNCHANGED this round):
// spill-free (256,2) shape, K=128 double-buffered chunks, counted vmcnt(8),
// LDS candidate collection with one coalesced end-flush, both-sides 16-slot
// XOR swizzle.
__global__ __launch_bounds__(256, 2)
void pass1_kernel(const float* __restrict__ x, const unsigned short* __restrict__ embh,
                  unsigned int* __restrict__ cand, int* __restrict__ cnt_out) {
    __shared__ unsigned short Bs[2][16384];       // 2 x 32 KB: 128 codes x 128 k, swizzled
    __shared__ unsigned int cand_lds[P1_BM * CAP];// 12.3 KB candidate buffer
    __shared__ float part[4][32];                 // per-wave per-row tile max
    __shared__ float tilemax[P1_BM];              // merged tile max
    __shared__ int   cnts[P1_BM];

    const int t    = threadIdx.x;
    const int w    = t >> 6;
    const int lane = t & 63;
    const int quad = lane >> 4;
    const int lm   = lane & 15;
    const int wr   = w >> 1;           // row group: rows wr*32 .. +31
    const int wc   = w & 1;            // col half: cols wc*64 .. +63
    const int row0 = blockIdx.x * P1_BM;

    if (t < P1_BM) cnts[t] = 0;

    // ---- A panel -> registers: afr[f][c] = bf16(x[row0+wr*32+f*16+lm][c*32+quad*8 ..+7])
    bf16x8 afr[2][8];
    #pragma unroll
    for (int f = 0; f < 2; ++f) {
        const float* xr = x + (size_t)(row0 + wr * 32 + f * 16 + lm) * DIMD + quad * 8;
        #pragma unroll
        for (int c = 0; c < 8; ++c) {
            const float4 v0 = *(const float4*)(xr + c * 32);
            const float4 v1 = *(const float4*)(xr + c * 32 + 4);
            bf16x8 h;
            h[0] = (short)f2bf(v0.x); h[1] = (short)f2bf(v0.y);
            h[2] = (short)f2bf(v0.z); h[3] = (short)f2bf(v0.w);
            h[4] = (short)f2bf(v1.x); h[5] = (short)f2bf(v1.y);
            h[6] = (short)f2bf(v1.z); h[7] = (short)f2bf(v1.w);
            afr[f][c] = h;
        }
    }

    // stage chunk m (c0=(m>>1)*128 codes, kcb=(m&1)*128 k) into Bs[buf]
    auto stage = [&](int buf, int m) {
        const int c0  = (m >> 1) * P1_BN;
        const int kcb = (m & 1) * 128;
        #pragma unroll
        for (int i = 0; i < 8; ++i) {
            const int seg = i * 4 + w;                         // 0..31, wave-uniform
            const int c   = seg * 4 + (lane >> 4);             // 0..127
            const int kk  = ((lane & 15) ^ (c & 15)) * 8;      // shorts
            const unsigned short* src = embh + (size_t)(c0 + c) * DIMD + kcb + kk;
            gload_lds16(src, &Bs[buf][seg * 512]);             // 1 KB per issue
        }
    };

    stage(0, 0);
    int buf = 0;

    float rmg[2][4];
    #pragma unroll
    for (int f = 0; f < 2; ++f)
        #pragma unroll
        for (int reg = 0; reg < 4; ++reg) rmg[f][reg] = -INFINITY;

    for (int tile = 0; tile < NT; ++tile) {
        const int c0 = tile * P1_BN;
        f32x4 acc[2][4];
        #pragma unroll
        for (int f = 0; f < 2; ++f)
            #pragma unroll
            for (int g = 0; g < 4; ++g) acc[f][g] = (f32x4){0.f, 0.f, 0.f, 0.f};

        #pragma unroll
        for (int kb = 0; kb < 2; ++kb) {
            const int m = tile * 2 + kb;
            __syncthreads();               // A: all waves done reading buf^1
            if (m + 1 < NCHUNK) {
                stage(buf ^ 1, m + 1);
                VM8();                     // wait chunk-m loads (8 newer in flight)
            } else {
                VM0();                     // last chunk
            }
            __syncthreads();               // B: chunk m fully in LDS

            // compute chunk m from Bs[buf]: K=128 = 4 MFMA K-steps
            #pragma unroll
            for (int ks = 0; ks < 4; ++ks) {
                bf16x8 b[4];
                #pragma unroll
                for (int g = 0; g < 4; ++g) {
                    const int c = wc * 64 + g * 16 + lm;     // c&15 == lm
                    b[g] = *(const bf16x8*)
                        &Bs[buf][c * 128 + ((((ks << 2) + quad) ^ lm) << 3)];
                }
                #pragma unroll
                for (int f = 0; f < 2; ++f)
                    #pragma unroll
                    for (int g = 0; g < 4; ++g)
                        acc[f][g] = __builtin_amdgcn_mfma_f32_16x16x32_bf16(
                            afr[f][kb * 4 + ks], b[g], acc[f][g], 0, 0, 0);
            }
            buf ^= 1;
        }

        // epilogue A: per-wave per-row max over this tile's 64 cols
        #pragma unroll
        for (int f = 0; f < 2; ++f) {
            f32x4 mm4;
            #pragma unroll
            for (int reg = 0; reg < 4; ++reg) {
                float mm = fmaxf(fmaxf(acc[f][0][reg], acc[f][1][reg]),
                                 fmaxf(acc[f][2][reg], acc[f][3][reg]));
                #pragma unroll
                for (int off = 1; off < 16; off <<= 1)
                    mm = fmaxf(mm, __shfl_xor(mm, off, 64));  // within quad group
                mm4[reg] = mm;
            }
            if (lm == 0)
                *(f32x4*)&part[w][f * 16 + quad * 4] = mm4;
        }

        // merge 2 col-waves per row group -> tile max, then prefix max
        __syncthreads();
        if (t < P1_BM) {
            const int trg = t >> 5, loc = t & 31;
            tilemax[t] = fmaxf(part[trg * 2][loc], part[trg * 2 + 1][loc]);
        }
        __syncthreads();

        // epilogue B: threshold vs global prefix max (tile-inclusive), collect to LDS
        #pragma unroll
        for (int f = 0; f < 2; ++f) {
            const f32x4 tm = *(const f32x4*)&tilemax[wr * 32 + f * 16 + quad * 4];
            #pragma unroll
            for (int reg = 0; reg < 4; ++reg) {
                rmg[f][reg] = fmaxf(rmg[f][reg], tm[reg]);
                const float thr = rmg[f][reg] - TAU2;
                const int r = wr * 32 + f * 16 + quad * 4 + reg;
                #pragma unroll
                for (int g = 0; g < 4; ++g) {
                    const float dv = acc[f][g][reg];
                    if (dv > thr) {
                        const int slot = atomicAdd(&cnts[r], 1);
                        if (slot < CAP) {
                            const unsigned int ub =
                                __builtin_bit_cast(unsigned int, fmaxf(dv, 0.0f));
                            cand_lds[r * CAP + slot] =
                                (ub & 0xFFFFF000u) |
                                (unsigned int)(c0 + wc * 64 + g * 16 + lm);
                        }
                    }
                }
            }
        }
    }
    __syncthreads();

    // flush: whole candidate buffer, coalesced
    {
        const uint4* src = (const uint4*)cand_lds;
        uint4* dst = (uint4*)(cand + (size_t)row0 * CAP);
        #pragma unroll
        for (int i = 0; i < P1_BM * CAP / 4 / 256; ++i)
            dst[i * 256 + t] = src[i * 256 + t];
    }
    if (t < P1_BM) cnt_out[row0 + t] = (cnts[t] > CAP) ? -1 : cnts[t];
}

// ---------------------------------------------------------------- kernel P2 (fused, v4)
// 4 rows per wave with cross-row prefetch pipelining + single-survivor fast
// path. Per row: re-filter stored candidates against the FINAL max dot; if
// exactly ONE survivor, it IS the argmin (re-rank of a singleton) -> skip
// staging/chain. Else stage survivors via async global_load_lds (one wait)
// and run the exact np-semantics re-rank from LDS: dist = fl(fl(sx-2*dot)+se),
// dot = sequential fp32 FMA chain (validated R5/R6). Next row's cnt/cand/sx/x
// loads are issued at the top of the current row so they fly under this row's
// stage-wait + chain. esh slots padded +1 float4 (4-bank skew, kills the
// slot-aligned conflicts seen in R8). Writes quantized + idx + loss partial.
__global__ __launch_bounds__(256, 4)
void pass2_kernel(const float* __restrict__ x, const float* __restrict__ emb,
                  const float* __restrict__ sx, const float* __restrict__ se,
                  const unsigned int* __restrict__ cand, const int* __restrict__ cnt,
                  float* __restrict__ out, float* __restrict__ partial) {
    __shared__ float4 xsh[4][64];
    __shared__ float4 esh[4][NS][65];     // +1 float4 pad per slot
    const int w = threadIdx.x >> 6, lane = threadIdx.x & 63;
    const int wid = blockIdx.x * 4 + w;   // 0..16383
    const float4* emb4 = (const float4*)emb;

    // prologue: loads for row 0
    int          n    = cnt[wid];
    unsigned int word = cand[(size_t)wid * CAP + lane];
    float        sxr  = sx[wid];
    float4       myx  = ((const float4*)(x + (size_t)wid * DIMD))[lane];

    #pragma unroll
    for (int r = 0; r < 4; ++r) {
        const int row = wid + r * P2_WAVES;

        // prefetch next row (overlaps this row's stage-wait + FMA chain)
        int n2 = 0; unsigned int word2 = 0; float sxr2 = 0.0f; float4 myx2{};
        if (r < 3) {
            const int rn = wid + (r + 1) * P2_WAVES;
            n2    = cnt[rn];
            word2 = cand[(size_t)rn * CAP + lane];
            sxr2  = sx[rn];
            myx2  = ((const float4*)(x + (size_t)rn * DIMD))[lane];
        }

        xsh[w][lane] = myx;               // current row x -> LDS (wave-local)
        const float4* xs4 = &xsh[w][0];

        float bestd = INFINITY;
        int   bestc = 0x7fffffff;
        int   wslot = 0x7fffffff;
        bool  fast  = false;

        if (n >= 1 && n <= CAP) {
            const float dtil = (lane < n)
                ? __builtin_bit_cast(float, word & 0xFFFFF000u) : -INFINITY;
            const int code = (int)(word & 0xFFFu);   // garbage if lane>=n (masked)
            // wave max of stored (truncated) dots == final max - O(2.5e-6)
            float mx = dtil;
            #pragma unroll
            for (int off = 1; off < 64; off <<= 1)
                mx = fmaxf(mx, __shfl_xor(mx, off, 64));
            const bool active = (lane < n) && (dtil > mx - TAU2B);
            const unsigned long long mask = __ballot(active);
            const int nact = __popcll(mask);
            if (nact == 1) {
                // singleton survivor IS the exact argmin: no re-rank needed
                const int li = __ffsll(mask) - 1;
                bestc = __shfl(code, li, 64);        // uniform
                fast  = true;
            } else {
                const int slot = __popcll(mask & ((1ull << lane) - 1ull));
                // async-stage up to NS surviving rows: issue all, wait once
                unsigned long long mm = mask;
                const int ns = nact < NS ? nact : NS;
                for (int i = 0; i < ns; ++i) {
                    const int li = __ffsll(mm) - 1;
                    mm &= mm - 1;
                    const int bc = __shfl(code, li, 64);
                    gload_lds16(emb4 + (size_t)bc * 64 + lane, &esh[w][i][0]);
                }
                VM0();
                if (active) {
                    float a = 0.0f;
                    if (slot < NS) {
                        const float4* ep4 = &esh[w][slot][0];
                        #pragma unroll
                        for (int d4 = 0; d4 < DIMD / 4; ++d4) {
                            const float4 ev = ep4[d4];
                            const float4 xv = xs4[d4];
                            a = fmaf(xv.x, ev.x, a);
                            a = fmaf(xv.y, ev.y, a);
                            a = fmaf(xv.z, ev.z, a);
                            a = fmaf(xv.w, ev.w, a);
                        }
                    } else {  // rare: >NS survivors, read from global
                        const float4* ep4 = emb4 + (size_t)code * 64;
                        #pragma unroll
                        for (int d4 = 0; d4 < DIMD / 4; ++d4) {
                            const float4 ev = ep4[d4];
                            const float4 xv = xs4[d4];
                            a = fmaf(xv.x, ev.x, a);
                            a = fmaf(xv.y, ev.y, a);
                            a = fmaf(xv.z, ev.z, a);
                            a = fmaf(xv.w, ev.w, a);
                        }
                    }
                    const float t1 = sxr - 2.0f * a;   // fl(sx - 2*dot)
                    bestd = t1 + se[code];             // fl(t1 + se)
                    bestc = code;
                    wslot = slot;
                }
            }
        } else {
            // overflow / safety fallback: full exact scan (ascending per lane)
            for (int c = lane; c < KCODES; c += 64) {
                const float* ep = emb + (size_t)c * DIMD;
                float a = 0.0f;
                for (int d4 = 0; d4 < DIMD / 4; ++d4) {
                    const float4 xv = xs4[d4];
                    const float4 ev = ((const float4*)ep)[d4];
                    a = fmaf(xv.x, ev.x, a);
                    a = fmaf(xv.y, ev.y, a);
                    a = fmaf(xv.z, ev.z, a);
                    a = fmaf(xv.w, ev.w, a);
                }
                const float t1 = sxr - 2.0f * a;
                const float dd = t1 + se[c];
                if (dd < bestd || (dd == bestd && c < bestc)) { bestd = dd; bestc = c; }
            }
        }

        if (!fast) {
            // wave argmin, lexicographic (value, code): np first-occurrence
            #pragma unroll
            for (int off = 32; off > 0; off >>= 1) {
                const float od = __shfl_down(bestd, off, 64);
                const int   oc = __shfl_down(bestc, off, 64);
                const int   os = __shfl_down(wslot, off, 64);
                if (od < bestd || (od == bestd && oc < bestc)) {
                    bestd = od; bestc = oc; wslot = os;
                }
            }
            bestc = __shfl(bestc, 0, 64);   // broadcast winner
            wslot = __shfl(wslot, 0, 64);
        }

        // fused epilogue: quantized row (from LDS when staged), idx, loss partial
        const float4 e4 = (wslot < NS) ? esh[w][wslot][lane]
                                       : emb4[(size_t)bestc * 64 + lane];
        ((float4*)(out + (size_t)row * DIMD))[lane] = e4;
        const float dx = e4.x - myx.x, dy = e4.y - myx.y,
                    dz = e4.z - myx.z, dw = e4.w - myx.w;
        float s = dx * dx + dy * dy + dz * dz + dw * dw;
        #pragma unroll
        for (int off = 32; off > 0; off >>= 1) s += __shfl_down(s, off, 64);
        if (lane == 0) {
            partial[row] = s;
            out[QN + 1 + row] = (float)bestc;
        }

        // rotate prefetched state
        n = n2; word = word2; sxr = sxr2; myx = myx2;
    }
}

// ---------------------------------------------------------------- kernel L
// reduce 65536 per-row fp32 partials -> loss (LDS tree, double accum)
__global__ void loss_reduce_kernel(const float* __restrict__ partial, float* __restrict__ out) {
    const int t = threadIdx.x;           // 256 threads, 1 block
    double s = 0.0;
    for (int i = t; i < NROWS; i += 256) s += (double)partial[i];
    __shared__ double tsum[256];
    tsum[t] = s;
    __syncthreads();
    #pragma unroll
    for (int off = 128; off > 0; off >>= 1) {
        if (t < off) tsum[t] += tsum[t + off];
        __syncthreads();
    }
    if (t == 0) out[QN] = (float)(tsum[0] * (1.25 / (double)QN));
}

// ---------------------------------------------------------------- launcher
extern "C" void kernel_launch(void* const* d_in, const int* in_sizes, int n_in,
                              void* d_out, int out_size, void* d_ws, size_t ws_size,
                              hipStream_t stream) {
    const float* x   = (const float*)d_in[0];   // [65536, 256]
    const float* emb = (const float*)d_in[1];   // [4096, 256]
    float* out = (float*)d_out;                 // q[16777216] | loss[1] | idx[65536]

    char* ws = (char*)d_ws;
    unsigned short* embh = (unsigned short*)ws;           ws += (size_t)KCODES * DIMD * 2; // 2 MB
    float* sx  = (float*)ws;                              ws += (size_t)NROWS * 4;         // 256 KB
    float* se  = (float*)ws;                              ws += (size_t)KCODES * 4;        // 16 KB
    unsigned int* cand = (unsigned int*)ws;               ws += (size_t)NROWS * CAP * 4;   // 12.6 MB
    int*   cnt  = (int*)ws;                               ws += (size_t)NROWS * 4;         // 256 KB
    float* partial = (float*)ws;                                                           // 256 KB

    conv_emb_kernel<<<KCODES * DIMD / 4 / 256, 256, 0, stream>>>(emb, embh);
    sx_kernel<<<NROWS / 32, 256, 0, stream>>>(x, sx);
    se_kernel<<<KCODES / 32, 256, 0, stream>>>(emb, se);
    pass1_kernel<<<NROWS / P1_BM, 256, 0, stream>>>(x, embh, cand, cnt);
    pass2_kernel<<<P2_WAVES / 4, 256, 0, stream>>>(x, emb, sx, se, cand, cnt, out, partial);
    loss_reduce_kernel<<<1, 256, 0, stream>>>(partial, out);
}

// Round 10
// 742.368 us; speedup vs baseline: 1.0554x; 1.0554x over previous
//
#include <hip/hip_runtime.h>
#include <math.h>

// Problem constants (fixed by reference)
#define DIMD 256
#define KCODES 4096
#define NROWS 65536
#define QN (NROWS * DIMD)   // 16777216 quantized elements

// ---------------- pass1 (bf16 MFMA prune) parameters ----------------
constexpr int P1_BM = 64;      // rows per block (4 waves, 2x2 tiling)
constexpr int P1_BN = 128;     // codes per N-tile
constexpr int NT    = KCODES / P1_BN;   // 32 N-tiles
constexpr int NCHUNK = NT * 2;          // 64 chunks of 128 codes x 128 k
// Dot-scale margin: candidate iff dot > running_global_prefix_max - TAU2.
// Error stack (dot scale): bf16 operand rounding <=2.3e-4 (worst), np fp32
// quantization ~3e-5, dropped se <=0.8e-5  ->  TAU2 = 7.5e-4 is ~2.8x margin.
// Prefix max <= final max at every collection point -> superset of the
// final-max candidate set (E ~ 7/row). Stored word packs the MFMA dot
// (top-20 fp32 bits) + 12-bit code; pass2 recovers the FINAL max and
// re-filters to ~2-3/row before the exact re-rank. Key truncation < 2.5e-6
// covered by the +1e-5 pass2 margin. A SINGLETON survivor is therefore the
// exact argmin (the true argmin is always among survivors) -> fast path.
constexpr float TAU2 = 7.5e-4f;
constexpr float TAU2B = TAU2 + 1e-5f;   // pass2 re-filter margin (key truncation)
constexpr int CAP   = 48;      // candidate slots per row (overflow -> exact fallback)
constexpr int NS    = 6;       // pass2 LDS staging slots (survivors E~2-3)

typedef __attribute__((ext_vector_type(8))) short bf16x8;
typedef __attribute__((ext_vector_type(4))) float f32x4;

#define VM8() asm volatile("s_waitcnt vmcnt(8)" ::: "memory")
#define VM0() asm volatile("s_waitcnt vmcnt(0)" ::: "memory")

// RNE float -> bf16 bits (inputs finite; no NaN handling needed)
__device__ __forceinline__ unsigned short f2bf(float f) {
    unsigned int u = __builtin_bit_cast(unsigned int, f);
    u += 0x7fffu + ((u >> 16) & 1u);
    return (unsigned short)(u >> 16);
}

// Opaque barrier: forces v to be a rounded fp32 value (blocks FMA contraction)
__device__ __forceinline__ float opaque(float v) {
    asm volatile("" : "+v"(v));
    return v;
}

// async global->LDS, 16 B per lane, dest = wave-uniform base + lane*16
__device__ __forceinline__ void gload_lds16(const void* g, void* l) {
    __builtin_amdgcn_global_load_lds(
        (const __attribute__((address_space(1))) unsigned int*)g,
        (__attribute__((address_space(3))) unsigned int*)l, 16, 0, 0);
}

// ---------------------------------------------------------------- kernel Sx
// 8 lanes per row; lane j owns np accumulator r[j]. Bit-exact replication of
// the validated serial np pairwise_sum (combine tree via shfl_xor 1/2/4;
// IEEE add commutative -> bit-identical).
__global__ void sx_kernel(const float* __restrict__ x, float* __restrict__ sx) {
    const int j   = threadIdx.x & 7;
    const int row = blockIdx.x * 32 + (threadIdx.x >> 3);
    const float* p = x + (size_t)row * DIMD;
    float total = 0.0f;
    #pragma unroll
    for (int half = 0; half < 2; ++half) {
        const float* b = p + half * 128;
        const float v0 = b[j];
        float r = opaque(v0 * v0);
        #pragma unroll
        for (int i = 8; i < 128; i += 8) {
            const float v = b[i + j];
            r += opaque(v * v);
        }
        const float s1  = r  + __shfl_xor(r, 1, 64);
        const float s2  = s1 + __shfl_xor(s1, 2, 64);
        const float res = s2 + __shfl_xor(s2, 4, 64);
        total = (half == 0) ? res : (total + res);
    }
    if (j == 0) sx[row] = total;
}

// ---------------------------------------------------------------- kernel Se
__global__ void se_kernel(const float* __restrict__ emb, float* __restrict__ se) {
    const int j   = threadIdx.x & 7;
    const int row = blockIdx.x * 32 + (threadIdx.x >> 3);
    const float* p = emb + (size_t)row * DIMD;
    float total = 0.0f;
    #pragma unroll
    for (int half = 0; half < 2; ++half) {
        const float* b = p + half * 128;
        const float v0 = b[j];
        float r = opaque(v0 * v0);
        #pragma unroll
        for (int i = 8; i < 128; i += 8) {
            const float v = b[i + j];
            r += opaque(v * v);
        }
        const float s1  = r  + __shfl_xor(r, 1, 64);
        const float s2  = s1 + __shfl_xor(s1, 2, 64);
        const float res = s2 + __shfl_xor(s2, 4, 64);
        total = (half == 0) ? res : (total + res);
    }
    if (j == 0) se[row] = total;
}

// ---------------------------------------------------------------- conv emb->bf16
__global__ void conv_emb_kernel(const float* __restrict__ emb, unsigned short* __restrict__ embh) {
    const int i = blockIdx.x * blockDim.x + threadIdx.x;  // float4 index
    const float4 v = ((const float4*)emb)[i];
    ushort4 h;
    h.x = f2bf(v.x); h.y = f2bf(v.y); h.z = f2bf(v.z); h.w = f2bf(v.w);
    ((ushort4*)embh)[i] = h;
}

// ---------------------------------------------------------------- kernel P1
// Single-pass bf16 MFMA prune, v6 (validated R8; UNCHANGED):
// spill-free (256,2) shape, K=128 double-buffered chunks, counted vmcnt(8),
// LDS candidate collection with one coalesced end-flush, both-sides 16-slot
// XOR swizzle.
__global__ __launch_bounds__(256, 2)
void pass1_kernel(const float* __restrict__ x, const unsigned short* __restrict__ embh,
                  unsigned int* __restrict__ cand, int* __restrict__ cnt_out) {
    __shared__ unsigned short Bs[2][16384];       // 2 x 32 KB: 128 codes x 128 k, swizzled
    __shared__ unsigned int cand_lds[P1_BM * CAP];// 12.3 KB candidate buffer
    __shared__ float part[4][32];                 // per-wave per-row tile max
    __shared__ float tilemax[P1_BM];              // merged tile max
    __shared__ int   cnts[P1_BM];

    const int t    = threadIdx.x;
    const int w    = t >> 6;
    const int lane = t & 63;
    const int quad = lane >> 4;
    const int lm   = lane & 15;
    const int wr   = w >> 1;           // row group: rows wr*32 .. +31
    const int wc   = w & 1;            // col half: cols wc*64 .. +63
    const int row0 = blockIdx.x * P1_BM;

    if (t < P1_BM) cnts[t] = 0;

    // ---- A panel -> registers: afr[f][c] = bf16(x[row0+wr*32+f*16+lm][c*32+quad*8 ..+7])
    bf16x8 afr[2][8];
    #pragma unroll
    for (int f = 0; f < 2; ++f) {
        const float* xr = x + (size_t)(row0 + wr * 32 + f * 16 + lm) * DIMD + quad * 8;
        #pragma unroll
        for (int c = 0; c < 8; ++c) {
            const float4 v0 = *(const float4*)(xr + c * 32);
            const float4 v1 = *(const float4*)(xr + c * 32 + 4);
            bf16x8 h;
            h[0] = (short)f2bf(v0.x); h[1] = (short)f2bf(v0.y);
            h[2] = (short)f2bf(v0.z); h[3] = (short)f2bf(v0.w);
            h[4] = (short)f2bf(v1.x); h[5] = (short)f2bf(v1.y);
            h[6] = (short)f2bf(v1.z); h[7] = (short)f2bf(v1.w);
            afr[f][c] = h;
        }
    }

    // stage chunk m (c0=(m>>1)*128 codes, kcb=(m&1)*128 k) into Bs[buf]
    auto stage = [&](int buf, int m) {
        const int c0  = (m >> 1) * P1_BN;
        const int kcb = (m & 1) * 128;
        #pragma unroll
        for (int i = 0; i < 8; ++i) {
            const int seg = i * 4 + w;                         // 0..31, wave-uniform
            const int c   = seg * 4 + (lane >> 4);             // 0..127
            const int kk  = ((lane & 15) ^ (c & 15)) * 8;      // shorts
            const unsigned short* src = embh + (size_t)(c0 + c) * DIMD + kcb + kk;
            gload_lds16(src, &Bs[buf][seg * 512]);             // 1 KB per issue
        }
    };

    stage(0, 0);
    int buf = 0;

    float rmg[2][4];
    #pragma unroll
    for (int f = 0; f < 2; ++f)
        #pragma unroll
        for (int reg = 0; reg < 4; ++reg) rmg[f][reg] = -INFINITY;

    for (int tile = 0; tile < NT; ++tile) {
        const int c0 = tile * P1_BN;
        f32x4 acc[2][4];
        #pragma unroll
        for (int f = 0; f < 2; ++f)
            #pragma unroll
            for (int g = 0; g < 4; ++g) acc[f][g] = (f32x4){0.f, 0.f, 0.f, 0.f};

        #pragma unroll
        for (int kb = 0; kb < 2; ++kb) {
            const int m = tile * 2 + kb;
            __syncthreads();               // A: all waves done reading buf^1
            if (m + 1 < NCHUNK) {
                stage(buf ^ 1, m + 1);
                VM8();                     // wait chunk-m loads (8 newer in flight)
            } else {
                VM0();                     // last chunk
            }
            __syncthreads();               // B: chunk m fully in LDS

            // compute chunk m from Bs[buf]: K=128 = 4 MFMA K-steps
            #pragma unroll
            for (int ks = 0; ks < 4; ++ks) {
                bf16x8 b[4];
                #pragma unroll
                for (int g = 0; g < 4; ++g) {
                    const int c = wc * 64 + g * 16 + lm;     // c&15 == lm
                    b[g] = *(const bf16x8*)
                        &Bs[buf][c * 128 + ((((ks << 2) + quad) ^ lm) << 3)];
                }
                #pragma unroll
                for (int f = 0; f < 2; ++f)
                    #pragma unroll
                    for (int g = 0; g < 4; ++g)
                        acc[f][g] = __builtin_amdgcn_mfma_f32_16x16x32_bf16(
                            afr[f][kb * 4 + ks], b[g], acc[f][g], 0, 0, 0);
            }
            buf ^= 1;
        }

        // epilogue A: per-wave per-row max over this tile's 64 cols
        #pragma unroll
        for (int f = 0; f < 2; ++f) {
            f32x4 mm4;
            #pragma unroll
            for (int reg = 0; reg < 4; ++reg) {
                float mm = fmaxf(fmaxf(acc[f][0][reg], acc[f][1][reg]),
                                 fmaxf(acc[f][2][reg], acc[f][3][reg]));
                #pragma unroll
                for (int off = 1; off < 16; off <<= 1)
                    mm = fmaxf(mm, __shfl_xor(mm, off, 64));  // within quad group
                mm4[reg] = mm;
            }
            if (lm == 0)
                *(f32x4*)&part[w][f * 16 + quad * 4] = mm4;
        }

        // merge 2 col-waves per row group -> tile max, then prefix max
        __syncthreads();
        if (t < P1_BM) {
            const int trg = t >> 5, loc = t & 31;
            tilemax[t] = fmaxf(part[trg * 2][loc], part[trg * 2 + 1][loc]);
        }
        __syncthreads();

        // epilogue B: threshold vs global prefix max (tile-inclusive), collect to LDS
        #pragma unroll
        for (int f = 0; f < 2; ++f) {
            const f32x4 tm = *(const f32x4*)&tilemax[wr * 32 + f * 16 + quad * 4];
            #pragma unroll
            for (int reg = 0; reg < 4; ++reg) {
                rmg[f][reg] = fmaxf(rmg[f][reg], tm[reg]);
                const float thr = rmg[f][reg] - TAU2;
                const int r = wr * 32 + f * 16 + quad * 4 + reg;
                #pragma unroll
                for (int g = 0; g < 4; ++g) {
                    const float dv = acc[f][g][reg];
                    if (dv > thr) {
                        const int slot = atomicAdd(&cnts[r], 1);
                        if (slot < CAP) {
                            const unsigned int ub =
                                __builtin_bit_cast(unsigned int, fmaxf(dv, 0.0f));
                            cand_lds[r * CAP + slot] =
                                (ub & 0xFFFFF000u) |
                                (unsigned int)(c0 + wc * 64 + g * 16 + lm);
                        }
                    }
                }
            }
        }
    }
    __syncthreads();

    // flush: whole candidate buffer, coalesced
    {
        const uint4* src = (const uint4*)cand_lds;
        uint4* dst = (uint4*)(cand + (size_t)row0 * CAP);
        #pragma unroll
        for (int i = 0; i < P1_BM * CAP / 4 / 256; ++i)
            dst[i * 256 + t] = src[i * 256 + t];
    }
    if (t < P1_BM) cnt_out[row0 + t] = (cnts[t] > CAP) ? -1 : cnts[t];
}

// ---------------------------------------------------------------- kernel P2 (fused, v5)
// R8's 1-row-per-wave structure + R9's validated pieces only:
//  - esh slots padded +1 float4 (bank conflicts 7.4e6 -> 0, validated R9)
//  - singleton fast path: if the final-max re-filter leaves ONE survivor it
//    IS the exact argmin (TAU2B invariant) -> skip staging/VM0/chain/argmin.
// Multi-survivor path: async-stage survivor rows via global_load_lds (issue
// all, ONE vmcnt(0)), exact np-semantics re-rank from LDS:
// dist = fl(fl(sx-2*dot)+se), dot = sequential fp32 FMA chain (validated
// R5/R6). Winner read back from LDS. Writes quantized + idx + loss partial.
__global__ __launch_bounds__(256, 4)
void pass2_kernel(const float* __restrict__ x, const float* __restrict__ emb,
                  const float* __restrict__ sx, const float* __restrict__ se,
                  const unsigned int* __restrict__ cand, const int* __restrict__ cnt,
                  float* __restrict__ out, float* __restrict__ partial) {
    __shared__ float4 xsh[4][64];
    __shared__ float4 esh[4][NS][65];     // +1 float4 pad per slot (4-bank skew)
    const int w = threadIdx.x >> 6, lane = threadIdx.x & 63;
    const int row = blockIdx.x * 4 + w;
    const int n = cnt[row];                                          // load 1
    const unsigned int word = cand[(size_t)row * CAP + lane];        // load 2 (parallel)
    const float sxr = sx[row];                                       // load 3 (parallel)
    const float4 myx = ((const float4*)(x + (size_t)row * DIMD))[lane]; // load 4
    const float4* emb4 = (const float4*)emb;

    xsh[w][lane] = myx;
    const float4* xs4 = &xsh[w][0];

    float bestd = INFINITY;
    int   bestc = 0x7fffffff;
    int   wslot = 0x7fffffff;
    bool  fast  = false;

    if (n >= 1 && n <= CAP) {
        const float dtil = (lane < n)
            ? __builtin_bit_cast(float, word & 0xFFFFF000u) : -INFINITY;
        const int code = (int)(word & 0xFFFu);   // garbage if lane>=n (masked)
        // wave max of stored (truncated) dots == final max - O(2.5e-6)
        float mx = dtil;
        #pragma unroll
        for (int off = 1; off < 64; off <<= 1)
            mx = fmaxf(mx, __shfl_xor(mx, off, 64));
        const bool active = (lane < n) && (dtil > mx - TAU2B);
        const unsigned long long mask = __ballot(active);
        const int nact = __popcll(mask);
        if (nact == 1) {
            // singleton survivor IS the exact argmin: no re-rank needed
            const int li = __ffsll(mask) - 1;
            bestc = __shfl(code, li, 64);        // uniform
            fast  = true;
        } else {
            const int slot = __popcll(mask & ((1ull << lane) - 1ull));
            // async-stage up to NS surviving rows: issue all, wait once
            unsigned long long mm = mask;
            const int ns = nact < NS ? nact : NS;
            for (int i = 0; i < ns; ++i) {
                const int li = __ffsll(mm) - 1;
                mm &= mm - 1;
                const int bc = __shfl(code, li, 64);
                gload_lds16(emb4 + (size_t)bc * 64 + lane, &esh[w][i][0]);
            }
            VM0();
            if (active) {
                float a = 0.0f;
                if (slot < NS) {
                    const float4* ep4 = &esh[w][slot][0];
                    #pragma unroll
                    for (int d4 = 0; d4 < DIMD / 4; ++d4) {
                        const float4 ev = ep4[d4];
                        const float4 xv = xs4[d4];
                        a = fmaf(xv.x, ev.x, a);
                        a = fmaf(xv.y, ev.y, a);
                        a = fmaf(xv.z, ev.z, a);
                        a = fmaf(xv.w, ev.w, a);
                    }
                } else {  // rare: >NS survivors, read from global
                    const float4* ep4 = emb4 + (size_t)code * 64;
                    #pragma unroll
                    for (int d4 = 0; d4 < DIMD / 4; ++d4) {
                        const float4 ev = ep4[d4];
                        const float4 xv = xs4[d4];
                        a = fmaf(xv.x, ev.x, a);
                        a = fmaf(xv.y, ev.y, a);
                        a = fmaf(xv.z, ev.z, a);
                        a = fmaf(xv.w, ev.w, a);
                    }
                }
                const float t1 = sxr - 2.0f * a;   // fl(sx - 2*dot)
                bestd = t1 + se[code];             // fl(t1 + se)
                bestc = code;
                wslot = slot;
            }
        }
    } else {
        // overflow / safety fallback: full exact scan (ascending per lane)
        for (int c = lane; c < KCODES; c += 64) {
            const float* ep = emb + (size_t)c * DIMD;
            float a = 0.0f;
            for (int d4 = 0; d4 < DIMD / 4; ++d4) {
                const float4 xv = xs4[d4];
                const float4 ev = ((const float4*)ep)[d4];
                a = fmaf(xv.x, ev.x, a);
                a = fmaf(xv.y, ev.y, a);
                a = fmaf(xv.z, ev.z, a);
                a = fmaf(xv.w, ev.w, a);
            }
            const float t1 = sxr - 2.0f * a;
            const float dd = t1 + se[c];
            if (dd < bestd || (dd == bestd && c < bestc)) { bestd = dd; bestc = c; }
        }
    }

    if (!fast) {
        // wave argmin, lexicographic (value, code): np first-occurrence semantics
        #pragma unroll
        for (int off = 32; off > 0; off >>= 1) {
            const float od = __shfl_down(bestd, off, 64);
            const int   oc = __shfl_down(bestc, off, 64);
            const int   os = __shfl_down(wslot, off, 64);
            if (od < bestd || (od == bestd && oc < bestc)) {
                bestd = od; bestc = oc; wslot = os;
            }
        }
        bestc = __shfl(bestc, 0, 64);   // broadcast winner
        wslot = __shfl(wslot, 0, 64);
    }

    // fused epilogue: quantized row (from LDS when staged), idx, loss partial
    const float4 e4 = (wslot < NS) ? esh[w][wslot][lane]
                                   : emb4[(size_t)bestc * 64 + lane];
    ((float4*)(out + (size_t)row * DIMD))[lane] = e4;
    const float dx = e4.x - myx.x, dy = e4.y - myx.y,
                dz = e4.z - myx.z, dw = e4.w - myx.w;
    float s = dx * dx + dy * dy + dz * dz + dw * dw;
    #pragma unroll
    for (int off = 32; off > 0; off >>= 1) s += __shfl_down(s, off, 64);
    if (lane == 0) {
        partial[row] = s;
        out[QN + 1 + row] = (float)bestc;
    }
}

// ---------------------------------------------------------------- kernel L
// reduce 65536 per-row fp32 partials -> loss (LDS tree, double accum)
__global__ void loss_reduce_kernel(const float* __restrict__ partial, float* __restrict__ out) {
    const int t = threadIdx.x;           // 256 threads, 1 block
    double s = 0.0;
    for (int i = t; i < NROWS; i += 256) s += (double)partial[i];
    __shared__ double tsum[256];
    tsum[t] = s;
    __syncthreads();
    #pragma unroll
    for (int off = 128; off > 0; off >>= 1) {
        if (t < off) tsum[t] += tsum[t + off];
        __syncthreads();
    }
    if (t == 0) out[QN] = (float)(tsum[0] * (1.25 / (double)QN));
}

// ---------------------------------------------------------------- launcher
extern "C" void kernel_launch(void* const* d_in, const int* in_sizes, int n_in,
                              void* d_out, int out_size, void* d_ws, size_t ws_size,
                              hipStream_t stream) {
    const float* x   = (const float*)d_in[0];   // [65536, 256]
    const float* emb = (const float*)d_in[1];   // [4096, 256]
    float* out = (float*)d_out;                 // q[16777216] | loss[1] | idx[65536]

    char* ws = (char*)d_ws;
    unsigned short* embh = (unsigned short*)ws;           ws += (size_t)KCODES * DIMD * 2; // 2 MB
    float* sx  = (float*)ws;                              ws += (size_t)NROWS * 4;         // 256 KB
    float* se  = (float*)ws;                              ws += (size_t)KCODES * 4;        // 16 KB
    unsigned int* cand = (unsigned int*)ws;               ws += (size_t)NROWS * CAP * 4;   // 12.6 MB
    int*   cnt  = (int*)ws;                               ws += (size_t)NROWS * 4;         // 256 KB
    float* partial = (float*)ws;                                                           // 256 KB

    conv_emb_kernel<<<KCODES * DIMD / 4 / 256, 256, 0, stream>>>(emb, embh);
    sx_kernel<<<NROWS / 32, 256, 0, stream>>>(x, sx);
    se_kernel<<<KCODES / 32, 256, 0, stream>>>(emb, se);
    pass1_kernel<<<NROWS / P1_BM, 256, 0, stream>>>(x, embh, cand, cnt);
    pass2_kernel<<<NROWS / 4, 256, 0, stream>>>(x, emb, sx, se, cand, cnt, out, partial);
    loss_reduce_kernel<<<1, 256, 0, stream>>>(partial, out);
}